// Round 9
// baseline (1916.575 us; speedup 1.0000x reference)
//
#include <hip/hip_runtime.h>
#include <math.h>

#define HID 64
#define TST 2048
#define CH 16              // timesteps per chunk
#define NCH (TST / CH)     // 128 chunks
#define EPSN 1e-5f

typedef float v2f __attribute__((ext_vector_type(2)));

#define REP32(M) M(0) M(1) M(2) M(3) M(4) M(5) M(6) M(7) \
                 M(8) M(9) M(10) M(11) M(12) M(13) M(14) M(15) \
                 M(16) M(17) M(18) M(19) M(20) M(21) M(22) M(23) \
                 M(24) M(25) M(26) M(27) M(28) M(29) M(30) M(31)

#define REP64(M) \
  M(0) M(1) M(2) M(3) M(4) M(5) M(6) M(7) M(8) M(9) M(10) M(11) M(12) M(13) M(14) M(15) \
  M(16) M(17) M(18) M(19) M(20) M(21) M(22) M(23) M(24) M(25) M(26) M(27) M(28) M(29) M(30) M(31) \
  M(32) M(33) M(34) M(35) M(36) M(37) M(38) M(39) M(40) M(41) M(42) M(43) M(44) M(45) M(46) M(47) \
  M(48) M(49) M(50) M(51) M(52) M(53) M(54) M(55) M(56) M(57) M(58) M(59) M(60) M(61) M(62) M(63)

// pair list: (i, j0=2i, j1=2i+1) with literal tokens
#define REP32P(M) M(0,0,1) M(1,2,3) M(2,4,5) M(3,6,7) M(4,8,9) M(5,10,11) M(6,12,13) M(7,14,15) \
                  M(8,16,17) M(9,18,19) M(10,20,21) M(11,22,23) M(12,24,25) M(13,26,27) M(14,28,29) M(15,30,31) \
                  M(16,32,33) M(17,34,35) M(18,36,37) M(19,38,39) M(20,40,41) M(21,42,43) M(22,44,45) M(23,46,47) \
                  M(24,48,49) M(25,50,51) M(26,52,53) M(27,54,55) M(28,56,57) M(29,58,59) M(30,60,61) M(31,62,63)

// ---------------------------------------------------------------------------
// Kernel 1: x = GELU(LayerNorm(ce @ w1 + b1))  -> staged into d_out (unchanged)
// ---------------------------------------------------------------------------
__global__ void k_inproj(const float* __restrict__ ce, const float* __restrict__ w1,
                         const float* __restrict__ b1, const float* __restrict__ g1,
                         const float* __restrict__ be1, float* __restrict__ xout,
                         int nrows) {
    const int lane = threadIdx.x & 63;
    const int wave = threadIdx.x >> 6;
    const long row = (long)blockIdx.x * 4 + wave;
    if (row >= nrows) return;
    const float* cr = ce + row * 6;
    float acc = b1[lane];
    acc += cr[0] * w1[0 * HID + lane];
    acc += cr[1] * w1[1 * HID + lane];
    acc += cr[2] * w1[2 * HID + lane];
    acc += cr[3] * w1[3 * HID + lane];
    acc += cr[4] * w1[4 * HID + lane];
    acc += cr[5] * w1[5 * HID + lane];
    float s = acc;
#pragma unroll
    for (int m = 32; m >= 1; m >>= 1) s += __shfl_xor(s, m, 64);
    const float mean = s * (1.0f / 64.0f);
    const float d = acc - mean;
    float q = d * d;
#pragma unroll
    for (int m = 32; m >= 1; m >>= 1) q += __shfl_xor(q, m, 64);
    const float var = q * (1.0f / 64.0f);
    const float xn = d * rsqrtf(var + EPSN) * g1[lane] + be1[lane];
    const float ge = 0.5f * xn * (1.0f + erff(xn * 0.70710678118654752440f));
    xout[row * HID + lane] = ge;
}

__device__ __forceinline__ float gru_step(float gr, float gz, float gn,
                                          float pr, float pz, float pn, float h) {
    const float r = 1.0f / (1.0f + __expf(-(gr + pr)));
    const float z = 1.0f / (1.0f + __expf(-(gz + pz)));
    const float pre = gn + r * pn;
    const float e2 = __expf(2.0f * pre);
    const float n = 1.0f - 2.0f / (e2 + 1.0f);
    return (1.0f - z) * n + z * h;
}

// ---------------------------------------------------------------------------
// Kernel 2: GRU scan, 4 waves (R8 structure) with the scan wave's matvec
// operands moved OFF the LDS pipe via SGPR replication.
//
// Unified model of R0-R8 (all 1830-1880 cy/step): the per-CU LDS pipe at
// ~6 cy/wave-op carries ~2400 ops/chunk (19k cy of 29k measured) — the
// wave-uniform b64 broadcast reads of the matvec operands are the floor
// (R7's readlane-everywhere removed LDS but paid 7 waves x 256 VALU inst
// -> issue-bound at the same time; the fix must be scan-wave-only).
// Wave 0 now: h_reg (lane = output dim) -> 64 v_readlane (literal lanes)
// -> 64 scalars h0..h63 in SGPRs -> 192 v_fmac_f32 vacc, s_hj, v_Wj
// against the AGPR-pinned A/B/C pairs (same names/allocation as R8,
// accessed .x/.y). hbuf deleted; gate partials pr/pz/pn stay in wave-0
// registers. Waves 1-3 unchanged (their LDS load ~1500 cy/chunk now fits
// under wave 0's ~10k cy/chunk compute). #pragma unroll 1 keeps the
// ~300-inst t-body inside I$.
// ---------------------------------------------------------------------------
__global__ __launch_bounds__(256, 1)
__attribute__((amdgpu_waves_per_eu(1, 1)))
void k_gru(float* xo,
           const float* __restrict__ W_ih, const float* __restrict__ b_ih,
           const float* __restrict__ W_hh, const float* __restrict__ b_hh,
           const float* __restrict__ w2, const float* __restrict__ b2,
           const float* __restrict__ g2, const float* __restrict__ be2) {
    __shared__ __align__(16) float4 xbuf[2][CH][16];    // 8 KB  x chunks
    __shared__ __align__(16) float gibuf[2][CH][192];   // 24 KB gi preacts
    __shared__ __align__(16) float hist[2][CH][HID];    // 8 KB  h history

    const int tid = threadIdx.x;
    const int lane = tid & 63;
    const int wv = tid >> 6;
    float* xb = xo + (size_t)blockIdx.x * TST * HID;

#define DECLW(i) v2f A##i = {0.f, 0.f}, B##i = {0.f, 0.f}, C##i = {0.f, 0.f};
    REP32(DECLW)
    float sc0 = 0.f, sc1 = 0.f, sc2 = 0.f;   // per-wave scalar params

    if (wv == 0) {
        const v2f* r0 = (const v2f*)(W_hh + (size_t)lane * HID);
        const v2f* r1 = (const v2f*)(W_hh + (size_t)(64 + lane) * HID);
        const v2f* r2 = (const v2f*)(W_hh + (size_t)(128 + lane) * HID);
#define LW0(i) A##i = r0[i]; B##i = r1[i]; C##i = r2[i];
        REP32(LW0)
        sc0 = b_hh[lane]; sc1 = b_hh[64 + lane]; sc2 = b_hh[128 + lane];
    } else if (wv == 1) {
        const v2f* rA = (const v2f*)(W_ih + (size_t)lane * HID);
        const v2f* rB = (const v2f*)(W_ih + (size_t)(128 + lane) * HID);
#define LW1(i) A##i = rA[i]; B##i = rB[i];
        REP32(LW1)
        sc0 = b_ih[lane]; sc1 = b_ih[128 + lane];
    } else if (wv == 2) {
        const v2f* rC = (const v2f*)(W_ih + (size_t)(64 + lane) * HID);
#define LW2(i) A##i = rC[i];
        REP32(LW2)
        sc0 = b_ih[64 + lane];
    } else {
#define LW3(i) A##i.x = w2[(size_t)(2 * (i)) * HID + lane]; \
               A##i.y = w2[(size_t)(2 * (i) + 1) * HID + lane];
        REP32(LW3)
        sc0 = b2[lane]; sc1 = g2[lane]; sc2 = be2[lane];
    }

    // Park weights in the AGPR file (uniform allocation across waves, as R8).
#define PINW(i) asm volatile("" : "+a"(A##i), "+a"(B##i), "+a"(C##i));
    REP32(PINW)

    {
        const float4* src = (const float4*)xb;
        ((float4*)xbuf[0])[tid] = src[tid];
    }
    float h_reg = 0.0f;
    float pr = sc0, pz = sc1, pn = sc2;   // wave 0: matvec(h(-1)=0)+bias = bias
    __syncthreads();

    // SGPR replication of h (wave 0 only)
#define RLD(j) const float h##j = __int_as_float(__builtin_amdgcn_readlane(hI, j));

    // scan matvec: 2 fmas per (i,j0,j1) per gate, 4 accumulator chains each
#define SFM(i, j0, j1) \
    if (((i) & 3) == 0) { \
        ar0 = fmaf(h##j0, A##i.x, ar0); ar0 = fmaf(h##j1, A##i.y, ar0); \
        az0 = fmaf(h##j0, B##i.x, az0); az0 = fmaf(h##j1, B##i.y, az0); \
        an0 = fmaf(h##j0, C##i.x, an0); an0 = fmaf(h##j1, C##i.y, an0); \
    } else if (((i) & 3) == 1) { \
        ar1 = fmaf(h##j0, A##i.x, ar1); ar1 = fmaf(h##j1, A##i.y, ar1); \
        az1 = fmaf(h##j0, B##i.x, az1); az1 = fmaf(h##j1, B##i.y, az1); \
        an1 = fmaf(h##j0, C##i.x, an1); an1 = fmaf(h##j1, C##i.y, an1); \
    } else if (((i) & 3) == 2) { \
        ar2 = fmaf(h##j0, A##i.x, ar2); ar2 = fmaf(h##j1, A##i.y, ar2); \
        az2 = fmaf(h##j0, B##i.x, az2); az2 = fmaf(h##j1, B##i.y, az2); \
        an2 = fmaf(h##j0, C##i.x, an2); an2 = fmaf(h##j1, C##i.y, an2); \
    } else { \
        ar3 = fmaf(h##j0, A##i.x, ar3); ar3 = fmaf(h##j1, A##i.y, ar3); \
        az3 = fmaf(h##j0, B##i.x, az3); az3 = fmaf(h##j1, B##i.y, az3); \
        an3 = fmaf(h##j0, C##i.x, an3); an3 = fmaf(h##j1, C##i.y, an3); \
    }

    for (int p = 0; p <= NCH + 1; ++p) {
        if (wv == 0) {
            if (p >= 1 && p <= NCH) {
                const int c = p - 1;
                const float* gp = (const float*)gibuf[c & 1];
                float* hp = (float*)hist[c & 1];
#pragma unroll 1
                for (int t = 0; t < CH; ++t) {
                    const float gr = gp[t * 192 + lane];
                    const float gz = gp[t * 192 + 64 + lane];
                    const float gn = gp[t * 192 + 128 + lane];
                    h_reg = gru_step(gr, gz, gn, pr, pz, pn, h_reg);
                    hp[t * HID + lane] = h_reg;
                    const int hI = __float_as_int(h_reg);
                    REP64(RLD)
                    float ar0 = 0.f, ar1 = 0.f, ar2 = 0.f, ar3 = 0.f;
                    float az0 = 0.f, az1 = 0.f, az2 = 0.f, az3 = 0.f;
                    float an0 = 0.f, an1 = 0.f, an2 = 0.f, an3 = 0.f;
                    REP32P(SFM)
                    pr = ((ar0 + ar1) + (ar2 + ar3)) + sc0;
                    pz = ((az0 + az1) + (az2 + az3)) + sc1;
                    pn = ((an0 + an1) + (an2 + an3)) + sc2;
                }
            }
        } else if (wv == 1 || wv == 2) {
            if (p < NCH) {
                const float4* xc = (const float4*)xbuf[p & 1];
                float* gp = (float*)gibuf[p & 1];
#pragma unroll 1
                for (int t = 0; t < CH; ++t) {
                    const v2f* xv = (const v2f*)(xc + t * 16);
                    v2f aA0 = {0.f, 0.f}, aA1 = {0.f, 0.f};
                    v2f aB0 = {0.f, 0.f}, aB1 = {0.f, 0.f};
                    if (wv == 1) {
#define GFMA1(i) { const v2f x2 = xv[i]; \
                   if ((i) & 1) { aA1 += A##i * x2; aB1 += B##i * x2; } \
                   else         { aA0 += A##i * x2; aB0 += B##i * x2; } }
                        REP32(GFMA1)
                        gp[t * 192 + lane] = aA0.x + aA0.y + aA1.x + aA1.y + sc0;
                        gp[t * 192 + 128 + lane] = aB0.x + aB0.y + aB1.x + aB1.y + sc1;
                    } else {
#define GFMA2(i) { const v2f x2 = xv[i]; \
                   if ((i) & 1) { aA1 += A##i * x2; } \
                   else         { aA0 += A##i * x2; } }
                        REP32(GFMA2)
                        gp[t * 192 + 64 + lane] = aA0.x + aA0.y + aA1.x + aA1.y + sc0;
                    }
                }
            }
        } else {
            // ---- epilogue for chunk p-2: LN over 16 timesteps, 2 halves of 8 ----
            if (p >= 2) {
                const int ce = p - 2;
                const float* hp = (const float*)hist[ce & 1];
#pragma unroll 1
                for (int half = 0; half < 2; ++half) {
                    float yv[8], sv[8], qv[8];
#pragma unroll
                    for (int u = 0; u < 8; ++u) {
                        const int t = half * 8 + u;
                        const v2f* hr = (const v2f*)(hp + t * HID);
                        v2f a20 = {0.f, 0.f}, a21 = {0.f, 0.f};
#define EFMA(i) { const v2f h2 = hr[i]; \
                  if ((i) & 1) { a21 += A##i * h2; } else { a20 += A##i * h2; } }
                        REP32(EFMA)
                        yv[u] = sc0 + a20.x + a20.y + a21.x + a21.y;
                    }
#pragma unroll
                    for (int u = 0; u < 8; ++u) { sv[u] = yv[u]; qv[u] = yv[u] * yv[u]; }
#pragma unroll
                    for (int m = 32; m >= 1; m >>= 1) {
#pragma unroll
                        for (int u = 0; u < 8; ++u) sv[u] += __shfl_xor(sv[u], m, 64);
#pragma unroll
                        for (int u = 0; u < 8; ++u) qv[u] += __shfl_xor(qv[u], m, 64);
                    }
#pragma unroll
                    for (int u = 0; u < 8; ++u) {
                        const int t = half * 8 + u;
                        const float mean = sv[u] * (1.0f / 64.0f);
                        const float var = qv[u] * (1.0f / 64.0f) - mean * mean;
                        const float dd = yv[u] - mean;
                        xb[(size_t)(ce * CH + t) * HID + lane] =
                            dd * rsqrtf(var + EPSN) * sc1 + sc2;
                    }
                }
            }
            // prefetch x chunk p+1
            if (p + 1 < NCH) {
                const float4* src = (const float4*)(xb + (size_t)(p + 1) * CH * HID);
                float4* dst = (float4*)xbuf[(p + 1) & 1];
#pragma unroll
                for (int q2 = 0; q2 < 4; ++q2) dst[lane + q2 * 64] = src[lane + q2 * 64];
            }
        }
        __syncthreads();
    }
}

extern "C" void kernel_launch(void* const* d_in, const int* in_sizes, int n_in,
                              void* d_out, int out_size, void* d_ws, size_t ws_size,
                              hipStream_t stream) {
    const float* ce  = (const float*)d_in[0];
    const float* w1  = (const float*)d_in[1];
    const float* b1  = (const float*)d_in[2];
    const float* g1  = (const float*)d_in[3];
    const float* be1 = (const float*)d_in[4];
    const float* Wih = (const float*)d_in[5];
    const float* bih = (const float*)d_in[6];
    const float* Whh = (const float*)d_in[7];
    const float* bhh = (const float*)d_in[8];
    const float* w2  = (const float*)d_in[9];
    const float* b2  = (const float*)d_in[10];
    const float* g2  = (const float*)d_in[11];
    const float* be2 = (const float*)d_in[12];
    float* out = (float*)d_out;

    const int nrows = in_sizes[0] / 6;   // B*T
    const int B = nrows / TST;           // 256

    k_inproj<<<(nrows + 3) / 4, 256, 0, stream>>>(ce, w1, b1, g1, be1, out, nrows);
    k_gru<<<B, 256, 0, stream>>>(out, Wih, bih, Whh, bhh, w2, b2, g2, be2);
}